// Round 9
// baseline (208.873 us; speedup 1.0000x reference)
//
#include <hip/hip_runtime.h>
#include <hip/hip_bf16.h>
#include <stdint.h>

// ---- problem constants (B=2, T=2048, C=1024, H=16, hs=64) ----
#define BSZ   2
#define TT    2048
#define NH    16
#define HS    64
#define CC    1024
#define C3    3072
#define MT    4096            // B*T rows
#define E10   4.5399929762484854e-05f   // exp(-10)
#define SCL2  0.1803368801111204f       // 0.125 * log2(e)

typedef __bf16 bf16;
typedef __bf16 bf16x8 __attribute__((ext_vector_type(8)));
typedef float  f32x4  __attribute__((ext_vector_type(4)));
typedef short  s16x4  __attribute__((ext_vector_type(4)));

#define AS1 __attribute__((address_space(1)))
#define AS3 __attribute__((address_space(3)))

__device__ __forceinline__ void glds16(const bf16* g, bf16* l) {
    __builtin_amdgcn_global_load_lds((const AS1 void*)g, (AS3 void*)l, 16, 0, 0);
}

// =====================================================================
// convert_all with INLINE dtype detection: every block samples x[0:512)
// uint16 exponents, computes flag locally; block 0 publishes it.
// flag=0 -> bf16 inputs (no convert), flag=1 -> fp32 inputs.
// =====================================================================
#define NX8  (MT * CC / 8)          // 524288
#define NWA8 (C3 * CC / 8)          // 393216
#define NWP8 (CC * CC / 8)          // 131072
__global__ __launch_bounds__(256)
void convert_all(const float* __restrict__ x, const float* __restrict__ wa,
                 const float* __restrict__ wp, bf16* __restrict__ xd,
                 bf16* __restrict__ wad, bf16* __restrict__ wpd,
                 int* __restrict__ flag) {
    __shared__ int wsum[4];
    const int tid = threadIdx.x;
    const uint16_t* x16 = (const uint16_t*)x;
    int local = 0;
    {
        uint16_t u = x16[tid];
        int e = (u >> 7) & 0xFF; local += (e >= 96 && e <= 159);
        u = x16[tid + 256];
        e = (u >> 7) & 0xFF; local += (e >= 96 && e <= 159);
    }
    local += __shfl_xor(local, 1, 64);
    local += __shfl_xor(local, 2, 64);
    local += __shfl_xor(local, 4, 64);
    local += __shfl_xor(local, 8, 64);
    local += __shfl_xor(local, 16, 64);
    local += __shfl_xor(local, 32, 64);
    if ((tid & 63) == 0) wsum[tid >> 6] = local;
    __syncthreads();
    const int cnt = wsum[0] + wsum[1] + wsum[2] + wsum[3];
    const int f = (cnt >= 461) ? 0 : 1;
    if (blockIdx.x == 0 && tid == 0) *flag = f;
    if (f == 0) return;

    long i = (long)blockIdx.x * 256 + tid;
    const float* s; bf16* d; long off;
    if (i < NX8)             { s = x;  d = xd;  off = i; }
    else if (i < NX8 + NWA8) { s = wa; d = wad; off = i - NX8; }
    else                     { s = wp; d = wpd; off = i - NX8 - NWA8; }
    const float4* sp = reinterpret_cast<const float4*>(s) + off * 2;
    float4 a = sp[0], b = sp[1];
    bf16x8 r;
    r[0] = (bf16)a.x; r[1] = (bf16)a.y; r[2] = (bf16)a.z; r[3] = (bf16)a.w;
    r[4] = (bf16)b.x; r[5] = (bf16)b.y; r[6] = (bf16)b.z; r[7] = (bf16)b.w;
    reinterpret_cast<bf16x8*>(d)[off] = r;
}

// =====================================================================
// GEMM 128x128: C = A*B^T, dbuf single-barrier pipeline.
// v10: main-store blocks use SWAPPED mfma (bfv, af) so D-rows = C-cols:
// thread holds 4 CONSECUTIVE C-columns of one row -> 8B/16B packed
// stores (16 store instrs/thread instead of 64 scalar 2B stores).
// V-blocks (col0 >= split_col) keep the original operand order; their
// sigma-packed Vt store + fused Vtile sums depend on that layout.
// =====================================================================
__global__ __launch_bounds__(256)
void gemm_bt(const bf16* __restrict__ A0, const bf16* __restrict__ A1,
             const bf16* __restrict__ B0, const bf16* __restrict__ B1,
             void* __restrict__ Cmain, bf16* __restrict__ Cv,
             float* __restrict__ Vtile,
             const int* __restrict__ flag,
             int M, int N, int K, int lda, int ldb, int ldc,
             int split_col, int cf32_dyn) {
    __shared__ bf16 As[2][128 * 32];
    __shared__ bf16 Bs[2][128 * 32];

    const int f = *flag;
    const bf16* A = f ? A1 : A0;
    const bf16* B = f ? B1 : B0;
    const int cf32 = cf32_dyn & f;

    const int tid  = threadIdx.x;
    const int lane = tid & 63;
    const int wave = tid >> 6;
    const int wm   = wave >> 1;
    const int wn   = wave & 1;
    const int quad = lane >> 4;
    const int l16  = lane & 15;

    const int row0 = blockIdx.y * 128;
    const int col0 = blockIdx.x * 128;
    const bool mainblk = (split_col < 0 || col0 < split_col);

    const int srow = tid >> 2;
    const int skk  = (tid & 3) * 8;

    const bf16* Ap = A + (long)(row0 + srow) * lda + skk;
    const bf16* Bp = B + (long)(col0 + srow) * ldb + skk;

    auto stage = [&](int k0, int buf) {
        glds16(Ap + k0,                  &As[buf][wave * 512]);
        glds16(Ap + (long)64 * lda + k0, &As[buf][wave * 512 + 2048]);
        glds16(Bp + k0,                  &Bs[buf][wave * 512]);
        glds16(Bp + (long)64 * ldb + k0, &Bs[buf][wave * 512 + 2048]);
    };

    f32x4 acc[4][4] = {};
    stage(0, 0);

    for (int k0 = 0; k0 < K; k0 += 32) {
        const int buf = (k0 >> 5) & 1;
        __syncthreads();
        if (k0 + 32 < K) stage(k0 + 32, buf ^ 1);

        const bf16* Ac = As[buf];
        const bf16* Bc = Bs[buf];
        bf16x8 af[4], bfv[4];
#pragma unroll
        for (int mi = 0; mi < 4; ++mi)
            af[mi] = *reinterpret_cast<const bf16x8*>(&Ac[(wm * 64 + mi * 16 + l16) * 32 + quad * 8]);
#pragma unroll
        for (int ni = 0; ni < 4; ++ni)
            bfv[ni] = *reinterpret_cast<const bf16x8*>(&Bc[(wn * 64 + ni * 16 + l16) * 32 + quad * 8]);
        if (mainblk) {
            // swapped: D[row=C-col (quad*4+r), col=C-row (l16)]
#pragma unroll
            for (int mi = 0; mi < 4; ++mi)
#pragma unroll
                for (int ni = 0; ni < 4; ++ni)
                    acc[mi][ni] = __builtin_amdgcn_mfma_f32_16x16x32_bf16(bfv[ni], af[mi], acc[mi][ni], 0, 0, 0);
        } else {
#pragma unroll
            for (int mi = 0; mi < 4; ++mi)
#pragma unroll
                for (int ni = 0; ni < 4; ++ni)
                    acc[mi][ni] = __builtin_amdgcn_mfma_f32_16x16x32_bf16(af[mi], bfv[ni], acc[mi][ni], 0, 0, 0);
        }
    }

    if (mainblk) {
        // swapped store: thread owns row = mi*16+l16, cols ni*16+quad*4+(0..3)
#pragma unroll
        for (int mi = 0; mi < 4; ++mi) {
            const int row = row0 + wm * 64 + mi * 16 + l16;
#pragma unroll
            for (int ni = 0; ni < 4; ++ni) {
                const int col = col0 + wn * 64 + ni * 16 + quad * 4;
                if (cf32) {
                    *reinterpret_cast<f32x4*>(&((float*)Cmain)[(long)row * ldc + col]) = acc[mi][ni];
                } else {
                    bf16 outv[4];
#pragma unroll
                    for (int r = 0; r < 4; ++r) outv[r] = (bf16)acc[mi][ni][r];
                    *reinterpret_cast<uint2*>(&((bf16*)Cmain)[(long)row * ldc + col]) =
                        *reinterpret_cast<uint2*>(outv);
                }
            }
        }
    } else {
        // V store in Vt[bh][d][tc*64 + sigma(tloc)] layout (unswapped acc)
        const int h  = (col0 - split_col + wn * 64) >> 6;   // wave-uniform
        const int bq = row0 >> 11;
        const int tc = ((row0 & 2047) >> 6) + wm;
#pragma unroll
        for (int ni = 0; ni < 4; ++ni) {
            long vrow = (long)(bq * NH + h) * 64 + ni * 16 + l16;
#pragma unroll
            for (int mi = 0; mi < 4; ++mi) {
                bf16 outv[4];
#pragma unroll
                for (int r = 0; r < 4; ++r) outv[r] = (bf16)acc[mi][ni][r];
                *reinterpret_cast<uint2*>(&Cv[vrow * 2048 + tc * 64 + quad * 16 + mi * 4]) =
                    *reinterpret_cast<uint2*>(outv);
            }
        }
        // fused Vtile: per d-col sum over the 64-token tile
#pragma unroll
        for (int ni = 0; ni < 4; ++ni) {
            float s = 0.f;
#pragma unroll
            for (int mi = 0; mi < 4; ++mi)
#pragma unroll
                for (int r = 0; r < 4; ++r) s += acc[mi][ni][r];
            s += __shfl_xor(s, 16, 64);
            s += __shfl_xor(s, 32, 64);
            if (quad == 0)
                Vtile[((long)(bq * NH + h) * 32 + tc) * 64 + ni * 16 + l16] = s;
        }
    }
}

// =====================================================================
// GEMM 128x64 (gemm2): grid 512 = 2 blocks/CU. acc[4][2].
// v10: swapped mfma everywhere -> 8 packed stores/thread (was 32 scalar).
// =====================================================================
__global__ __launch_bounds__(256)
void gemm_bt64(const bf16* __restrict__ A0, const bf16* __restrict__ A1,
               const bf16* __restrict__ B0, const bf16* __restrict__ B1,
               void* __restrict__ C, const int* __restrict__ flag,
               int M, int N, int K, int lda, int ldb, int ldc, int cf32_dyn) {
    __shared__ bf16 As[2][128 * 32];
    __shared__ bf16 Bs[2][64 * 32];

    const int f = *flag;
    const bf16* A = f ? A1 : A0;
    const bf16* B = f ? B1 : B0;
    const int cf32 = cf32_dyn & f;

    const int tid  = threadIdx.x;
    const int lane = tid & 63;
    const int wave = tid >> 6;
    const int wm   = wave >> 1;
    const int wn   = wave & 1;
    const int quad = lane >> 4;
    const int l16  = lane & 15;

    const int row0 = blockIdx.y * 128;
    const int col0 = blockIdx.x * 64;

    const int srow = tid >> 2;
    const int skk  = (tid & 3) * 8;

    const bf16* Ap = A + (long)(row0 + srow) * lda + skk;
    const bf16* Bp = B + (long)(col0 + srow) * ldb + skk;

    auto stage = [&](int k0, int buf) {
        glds16(Ap + k0,                  &As[buf][wave * 512]);
        glds16(Ap + (long)64 * lda + k0, &As[buf][wave * 512 + 2048]);
        glds16(Bp + k0,                  &Bs[buf][wave * 512]);
    };

    f32x4 acc[4][2] = {};
    stage(0, 0);

    for (int k0 = 0; k0 < K; k0 += 32) {
        const int buf = (k0 >> 5) & 1;
        __syncthreads();
        if (k0 + 32 < K) stage(k0 + 32, buf ^ 1);

        const bf16* Ac = As[buf];
        const bf16* Bc = Bs[buf];
        bf16x8 af[4], bfv[2];
#pragma unroll
        for (int mi = 0; mi < 4; ++mi)
            af[mi] = *reinterpret_cast<const bf16x8*>(&Ac[(wm * 64 + mi * 16 + l16) * 32 + quad * 8]);
#pragma unroll
        for (int ni = 0; ni < 2; ++ni)
            bfv[ni] = *reinterpret_cast<const bf16x8*>(&Bc[(wn * 32 + ni * 16 + l16) * 32 + quad * 8]);
#pragma unroll
        for (int mi = 0; mi < 4; ++mi)
#pragma unroll
            for (int ni = 0; ni < 2; ++ni)
                acc[mi][ni] = __builtin_amdgcn_mfma_f32_16x16x32_bf16(bfv[ni], af[mi], acc[mi][ni], 0, 0, 0);
    }

    // swapped store: row = mi*16+l16, cols = ni*16+quad*4+(0..3)
#pragma unroll
    for (int mi = 0; mi < 4; ++mi) {
        const int row = row0 + wm * 64 + mi * 16 + l16;
#pragma unroll
        for (int ni = 0; ni < 2; ++ni) {
            const int col = col0 + wn * 32 + ni * 16 + quad * 4;
            if (cf32) {
                *reinterpret_cast<f32x4*>(&((float*)C)[(long)row * ldc + col]) = acc[mi][ni];
            } else {
                bf16 outv[4];
#pragma unroll
                for (int r = 0; r < 4; ++r) outv[r] = (bf16)acc[mi][ni][r];
                *reinterpret_cast<uint2*>(&((bf16*)C)[(long)row * ldc + col]) =
                    *reinterpret_cast<uint2*>(outv);
            }
        }
    }
}

// =====================================================================
// Flash attention v9 (unchanged, at its latency floor ~47us):
// 64q x 64k, 4 waves, 1024 blocks, 3 LDS buffers, depth-2 counted-vmcnt
// prefetch, cross-tile pipeline, Q pre-scaled, lp via ones-MFMA,
// in-block Vts suffix.
// =====================================================================
__global__ __launch_bounds__(256, 3)
void attn(bf16* __restrict__ qk, const bf16* __restrict__ Vt,
          const float* __restrict__ Vtile) {
    __shared__ bf16 Ks[3][64 * 64];
    __shared__ bf16 Vs[3][64 * 64];
    __shared__ float Vpart[4][64];

    const int tid  = threadIdx.x;
    const int lane = tid & 63;
    const int wave = tid >> 6;
    const int quad = lane >> 4;
    const int l16  = lane & 15;

    const int f2   = blockIdx.x;            // 0..1023
    const int xcd  = f2 & 7;
    const int slot = f2 >> 3;               // 0..127
    const int u    = slot & 3;              // {b, h&1}
    const int chunk = 31 - (slot >> 2);     // heavy first
    const int h = xcd * 2 + (u & 1);        // producer XCD = h>>1
    const int b = u >> 1;
    const int bh = b * 16 + h;
    const int q0 = chunk * 64;
    const long rbase = (long)b * TT;
    const int ktend = chunk + 1;

    const bf16* qp = qk + (rbase + q0 + wave * 16 + l16) * 2048 + h * HS;
    bf16x8 qf0 = *reinterpret_cast<const bf16x8*>(qp + quad * 8);
    bf16x8 qf1 = *reinterpret_cast<const bf16x8*>(qp + 32 + quad * 8);
#pragma unroll
    for (int j = 0; j < 8; ++j) {
        qf0[j] = (bf16)((float)qf0[j] * SCL2);
        qf1[j] = (bf16)((float)qf1[j] * SCL2);
    }

    f32x4 O[4] = {};
    f32x4 lpacc = {};
    const short one_bf16 = (short)0x3F80;
    const s16x4 ones = {one_bf16, one_bf16, one_bf16, one_bf16};

    const int rl  = lane >> 3;
    const int cs  = (lane & 7) ^ rl;
    const int row0dma = wave * 16 + rl;
    const bf16* kgb = qk + (rbase + row0dma) * 2048 + CC + h * HS + cs * 8;
    const bf16* vgb = Vt + ((long)(b * NH + h) * 64 + row0dma) * 2048 + cs * 8;
    const int sx = l16 & 7;

    auto stage = [&](int kt, int bi) {
        glds16(kgb + (long)(kt * 64) * 2048,     &Ks[bi][wave * 1024]);
        glds16(kgb + (long)(kt * 64 + 8) * 2048, &Ks[bi][wave * 1024 + 512]);
        glds16(vgb + kt * 64,                    &Vs[bi][wave * 1024]);
        glds16(vgb + 8 * 2048 + kt * 64,         &Vs[bi][wave * 1024 + 512]);
    };

    auto qkTile = [&](int bi, f32x4* Sn) {
        const bf16* Kc = Ks[bi];
        bf16x8 kf0[4], kf1[4];
#pragma unroll
        for (int g = 0; g < 4; ++g) {
            const int krow = g * 16 + l16;
            kf0[g] = *reinterpret_cast<const bf16x8*>(&Kc[krow * 64 + ((quad ^ sx) * 8)]);
            kf1[g] = *reinterpret_cast<const bf16x8*>(&Kc[krow * 64 + (((4 + quad) ^ sx) * 8)]);
        }
        __builtin_amdgcn_s_setprio(1);
#pragma unroll
        for (int g = 0; g < 4; ++g) {
            Sn[g] = __builtin_amdgcn_mfma_f32_16x16x32_bf16(kf0[g], qf0, Sn[g], 0, 0, 0);
            Sn[g] = __builtin_amdgcn_mfma_f32_16x16x32_bf16(kf1[g], qf1, Sn[g], 0, 0, 0);
        }
        __builtin_amdgcn_s_setprio(0);
    };
    auto vTile = [&](int bi, s16x4 vf[4][4]) {
        const bf16* Vc = Vs[bi];
#pragma unroll
        for (int dg = 0; dg < 4; ++dg) {
            const int vrow = dg * 16 + l16;
            union { uint4 u4; s16x4 s[2]; } ua, ub;
            ua.u4 = *reinterpret_cast<const uint4*>(&Vc[vrow * 64 + (((2 * quad) ^ sx) * 8)]);
            ub.u4 = *reinterpret_cast<const uint4*>(&Vc[vrow * 64 + (((2 * quad + 1) ^ sx) * 8)]);
            vf[dg][0] = ua.s[0]; vf[dg][1] = ua.s[1];
            vf[dg][2] = ub.s[0]; vf[dg][3] = ub.s[1];
        }
    };

    stage(0, 0);
    stage(ktend > 1 ? 1 : 0, 1);
    asm volatile("s_waitcnt vmcnt(4)" ::: "memory");
    __builtin_amdgcn_s_barrier();
    __builtin_amdgcn_sched_barrier(0);

    f32x4 Sc[4] = {};
    s16x4 vc[4][4] = {};
    qkTile(0, Sc);
    vTile(0, vc);

    int rb = 1;                 // buffer of tile kt+1
    int sb = 2;                 // slot for stage(kt+2)
    for (int kt = 0; kt < ktend; ++kt) {
        int nkt = kt + 2; nkt = (nkt < ktend) ? nkt : (ktend - 1);
        stage(nkt, sb);
        asm volatile("s_waitcnt vmcnt(4)" ::: "memory");
        __builtin_amdgcn_s_barrier();
        __builtin_amdgcn_sched_barrier(0);

        f32x4 Sn[4] = {};
        s16x4 vn[4][4] = {};
        if (kt + 1 < ktend) {
            qkTile(rb, Sn);
            vTile(rb, vn);
        }

        const bool dtile = (kt == ktend - 1);
        const int ql = wave * 16 + l16;
        s16x4 pk[4];
#pragma unroll
        for (int g = 0; g < 4; ++g) {
#pragma unroll
            for (int r = 0; r < 4; ++r) {
                float p = __builtin_exp2f(Sc[g][r]);
                if (dtile) {
                    int kl = g * 16 + quad * 4 + r;
                    p = (kl > ql) ? E10 : p;
                }
                union { bf16 b_; short s_; } u2;
                u2.b_ = (bf16)p;
                pk[g][r] = u2.s_;
            }
        }

        __builtin_amdgcn_s_setprio(1);
#pragma unroll
        for (int dg = 0; dg < 4; ++dg) {
            O[dg] = __builtin_amdgcn_mfma_f32_16x16x16bf16_1k(vc[dg][0], pk[0], O[dg], 0, 0, 0);
            O[dg] = __builtin_amdgcn_mfma_f32_16x16x16bf16_1k(vc[dg][1], pk[1], O[dg], 0, 0, 0);
            O[dg] = __builtin_amdgcn_mfma_f32_16x16x16bf16_1k(vc[dg][2], pk[2], O[dg], 0, 0, 0);
            O[dg] = __builtin_amdgcn_mfma_f32_16x16x16bf16_1k(vc[dg][3], pk[3], O[dg], 0, 0, 0);
        }
        lpacc = __builtin_amdgcn_mfma_f32_16x16x16bf16_1k(ones, pk[0], lpacc, 0, 0, 0);
        lpacc = __builtin_amdgcn_mfma_f32_16x16x16bf16_1k(ones, pk[1], lpacc, 0, 0, 0);
        lpacc = __builtin_amdgcn_mfma_f32_16x16x16bf16_1k(ones, pk[2], lpacc, 0, 0, 0);
        lpacc = __builtin_amdgcn_mfma_f32_16x16x16bf16_1k(ones, pk[3], lpacc, 0, 0, 0);
        __builtin_amdgcn_s_setprio(0);

#pragma unroll
        for (int g = 0; g < 4; ++g) Sc[g] = Sn[g];
#pragma unroll
        for (int dg = 0; dg < 4; ++dg)
#pragma unroll
            for (int j = 0; j < 4; ++j) vc[dg][j] = vn[dg][j];

        rb = (rb == 2) ? 0 : rb + 1;
        sb = (sb == 2) ? 0 : sb + 1;
    }

    // in-block Vts suffix: sum Vtile[bh][kt][d] for kt in [ktend,32)
    {
        float s = 0.f;
        for (int kt = ktend + wave; kt < 32; kt += 4)
            s += Vtile[((long)bh * 32 + kt) * 64 + lane];
        Vpart[wave][lane] = s;
    }
    __syncthreads();

    const int nfut = TT - ktend * 64;
    const float l = lpacc[0] + (float)nfut * E10;
    const float invl = 1.0f / l;

    bf16* yp = qk + (rbase + q0 + wave * 16 + l16) * 2048 + h * HS;
#pragma unroll
    for (int dg = 0; dg < 4; ++dg) {
        bf16 outv[4];
#pragma unroll
        for (int r = 0; r < 4; ++r) {
            const int d = dg * 16 + quad * 4 + r;
            float vts = Vpart[0][d] + Vpart[1][d] + Vpart[2][d] + Vpart[3][d];
            float o = O[dg][r] + E10 * vts;
            outv[r] = (bf16)(o * invl);
        }
        *reinterpret_cast<uint2*>(yp + dg * 16 + quad * 4) =
            *reinterpret_cast<uint2*>(outv);
    }
}

// =====================================================================
extern "C" void kernel_launch(void* const* d_in, const int* in_sizes, int n_in,
                              void* d_out, int out_size, void* d_ws, size_t ws_size,
                              hipStream_t stream) {
    const void* x      = d_in[0];
    const void* w_attn = d_in[1];
    const void* w_proj = d_in[2];

    // ws (~27.8 MB): qk | Vt | flag | (pad) | wp_cvt | Vtile
    char* ws = (char*)d_ws;
    bf16*  qk     = (bf16*)ws;                                    // 16,777,216 B
    bf16*  Vt     = (bf16*)(ws + (size_t)MT * 2048 * 2);          //  8,388,608 B
    char*  p2     = ws + (size_t)MT * 2048 * 2 + (size_t)32 * 64 * 2048 * 2;
    int*   flag   = (int*)p2;
    bf16*  wp_cvt = (bf16*)(p2 + 256 + 32 * 33 * 64 * 4);         //  2,097,152 B
    float* Vtile  = (float*)((char*)wp_cvt + (size_t)CC * CC * 2);//    262,144 B

    // d_out scratch (dead-by-ordering): x_cvt/wa_cvt consumed by gemm1;
    // gemm2 is the only writer of d_out afterwards.
    bf16* x_cvt  = (bf16*)d_out;
    bf16* wa_cvt = (bf16*)d_out + (size_t)MT * CC;

    // convert (with inline dtype detect; block 0 publishes flag)
    convert_all<<<(NX8 + NWA8 + NWP8) / 256, 256, 0, stream>>>(
        (const float*)x, (const float*)w_attn, (const float*)w_proj,
        x_cvt, wa_cvt, wp_cvt, flag);

    // gemm1: qkv projection. cols<2048 (Q,K) -> qk (ldc 2048, wide stores);
    // cols>=2048 (V) -> Vt directly (sigma-packed) + fused Vtile sums.
    gemm_bt<<<dim3(C3 / 128, MT / 128), 256, 0, stream>>>(
        (const bf16*)x, x_cvt, (const bf16*)w_attn, wa_cvt, qk, Vt, Vtile, flag,
        MT, C3, CC, CC, CC, /*ldc*/2048, /*split*/2048, /*cf32*/0);

    // attention (cross-tile pipelined, in-block Vts suffix); y -> Q cols
    attn<<<dim3(1024), 256, 0, stream>>>(qk, Vt, Vtile);

    // gemm2: out = y @ w_proj^T  [4096, 1024] — 128x64 tiles, wide stores
    gemm_bt64<<<dim3(CC / 64, MT / 128), 256, 0, stream>>>(
        qk, qk, (const bf16*)w_proj, wp_cvt, d_out, flag,
        MT, CC, CC, /*lda*/2048, CC, CC, /*cf32*/1);
}

// Round 10
// 175.553 us; speedup vs baseline: 1.1898x; 1.1898x over previous
//
#include <hip/hip_runtime.h>
#include <hip/hip_bf16.h>
#include <stdint.h>

// ---- problem constants (B=2, T=2048, C=1024, H=16, hs=64) ----
#define BSZ   2
#define TT    2048
#define NH    16
#define HS    64
#define CC    1024
#define C3    3072
#define MT    4096            // B*T rows
#define E10   4.5399929762484854e-05f   // exp(-10)
#define SCL2  0.1803368801111204f       // 0.125 * log2(e)

typedef __bf16 bf16;
typedef __bf16 bf16x8 __attribute__((ext_vector_type(8)));
typedef float  f32x4  __attribute__((ext_vector_type(4)));
typedef short  s16x4  __attribute__((ext_vector_type(4)));

#define AS1 __attribute__((address_space(1)))
#define AS3 __attribute__((address_space(3)))

__device__ __forceinline__ void glds16(const bf16* g, bf16* l) {
    __builtin_amdgcn_global_load_lds((const AS1 void*)g, (AS3 void*)l, 16, 0, 0);
}

// =====================================================================
// convert_all with INLINE dtype detection: every block samples x[0:512)
// uint16 exponents, computes flag locally; block 0 publishes it.
// flag=0 -> bf16 inputs (no convert), flag=1 -> fp32 inputs.
// =====================================================================
#define NX8  (MT * CC / 8)          // 524288
#define NWA8 (C3 * CC / 8)          // 393216
#define NWP8 (CC * CC / 8)          // 131072
__global__ __launch_bounds__(256)
void convert_all(const float* __restrict__ x, const float* __restrict__ wa,
                 const float* __restrict__ wp, bf16* __restrict__ xd,
                 bf16* __restrict__ wad, bf16* __restrict__ wpd,
                 int* __restrict__ flag) {
    __shared__ int wsum[4];
    const int tid = threadIdx.x;
    const uint16_t* x16 = (const uint16_t*)x;
    int local = 0;
    {
        uint16_t u = x16[tid];
        int e = (u >> 7) & 0xFF; local += (e >= 96 && e <= 159);
        u = x16[tid + 256];
        e = (u >> 7) & 0xFF; local += (e >= 96 && e <= 159);
    }
    local += __shfl_xor(local, 1, 64);
    local += __shfl_xor(local, 2, 64);
    local += __shfl_xor(local, 4, 64);
    local += __shfl_xor(local, 8, 64);
    local += __shfl_xor(local, 16, 64);
    local += __shfl_xor(local, 32, 64);
    if ((tid & 63) == 0) wsum[tid >> 6] = local;
    __syncthreads();
    const int cnt = wsum[0] + wsum[1] + wsum[2] + wsum[3];
    const int f = (cnt >= 461) ? 0 : 1;
    if (blockIdx.x == 0 && tid == 0) *flag = f;
    if (f == 0) return;

    long i = (long)blockIdx.x * 256 + tid;
    const float* s; bf16* d; long off;
    if (i < NX8)             { s = x;  d = xd;  off = i; }
    else if (i < NX8 + NWA8) { s = wa; d = wad; off = i - NX8; }
    else                     { s = wp; d = wpd; off = i - NX8 - NWA8; }
    const float4* sp = reinterpret_cast<const float4*>(s) + off * 2;
    float4 a = sp[0], b = sp[1];
    bf16x8 r;
    r[0] = (bf16)a.x; r[1] = (bf16)a.y; r[2] = (bf16)a.z; r[3] = (bf16)a.w;
    r[4] = (bf16)b.x; r[5] = (bf16)b.y; r[6] = (bf16)b.z; r[7] = (bf16)b.w;
    reinterpret_cast<bf16x8*>(d)[off] = r;
}

// =====================================================================
// GEMM 128x128: C = A*B^T, dbuf single-barrier pipeline (v9 structure,
// unswapped MFMA everywhere). v11: main-store path goes through an
// LDS-staged epilogue: acc -> Ce[128][132] bf16 (stride 132 => the
// quad-row scatter lands on 32 distinct banks, conflict-free), barrier,
// then 8 fully-coalesced 16B stores/thread (16 lanes x 16B = 256B runs)
// instead of 64 scalar 2B stores. V-blocks keep sigma store + Vtile.
// =====================================================================
__global__ __launch_bounds__(256)
void gemm_bt(const bf16* __restrict__ A0, const bf16* __restrict__ A1,
             const bf16* __restrict__ B0, const bf16* __restrict__ B1,
             void* __restrict__ Cmain, bf16* __restrict__ Cv,
             float* __restrict__ Vtile,
             const int* __restrict__ flag,
             int M, int N, int K, int lda, int ldb, int ldc,
             int split_col, int cf32_dyn) {
    // union: staging (As 16KB | Bs 16KB) / epilogue Ce 128x132 bf16 (33792B)
    __shared__ __align__(16) char smem[33792];
    bf16* As0 = (bf16*)smem;            // [2][128*32]
    bf16* Bs0 = (bf16*)(smem + 16384);  // [2][128*32]

    const int f = *flag;
    const bf16* A = f ? A1 : A0;
    const bf16* B = f ? B1 : B0;
    const int cf32 = cf32_dyn & f;

    const int tid  = threadIdx.x;
    const int lane = tid & 63;
    const int wave = tid >> 6;
    const int wm   = wave >> 1;
    const int wn   = wave & 1;
    const int quad = lane >> 4;
    const int l16  = lane & 15;

    const int row0 = blockIdx.y * 128;
    const int col0 = blockIdx.x * 128;
    const bool mainblk = (split_col < 0 || col0 < split_col);

    const int srow = tid >> 2;
    const int skk  = (tid & 3) * 8;

    const bf16* Ap = A + (long)(row0 + srow) * lda + skk;
    const bf16* Bp = B + (long)(col0 + srow) * ldb + skk;

    auto stage = [&](int k0, int buf) {
        glds16(Ap + k0,                  As0 + buf * 4096 + wave * 512);
        glds16(Ap + (long)64 * lda + k0, As0 + buf * 4096 + wave * 512 + 2048);
        glds16(Bp + k0,                  Bs0 + buf * 4096 + wave * 512);
        glds16(Bp + (long)64 * ldb + k0, Bs0 + buf * 4096 + wave * 512 + 2048);
    };

    f32x4 acc[4][4] = {};
    stage(0, 0);

    for (int k0 = 0; k0 < K; k0 += 32) {
        const int buf = (k0 >> 5) & 1;
        __syncthreads();
        if (k0 + 32 < K) stage(k0 + 32, buf ^ 1);

        const bf16* Ac = As0 + buf * 4096;
        const bf16* Bc = Bs0 + buf * 4096;
        bf16x8 af[4], bfv[4];
#pragma unroll
        for (int mi = 0; mi < 4; ++mi)
            af[mi] = *reinterpret_cast<const bf16x8*>(&Ac[(wm * 64 + mi * 16 + l16) * 32 + quad * 8]);
#pragma unroll
        for (int ni = 0; ni < 4; ++ni)
            bfv[ni] = *reinterpret_cast<const bf16x8*>(&Bc[(wn * 64 + ni * 16 + l16) * 32 + quad * 8]);
#pragma unroll
        for (int mi = 0; mi < 4; ++mi)
#pragma unroll
            for (int ni = 0; ni < 4; ++ni)
                acc[mi][ni] = __builtin_amdgcn_mfma_f32_16x16x32_bf16(af[mi], bfv[ni], acc[mi][ni], 0, 0, 0);
    }

    if (mainblk) {
        if (cf32) {
            // fallback (unused by current launches): scalar f32 stores
#pragma unroll
            for (int mi = 0; mi < 4; ++mi)
#pragma unroll
                for (int ni = 0; ni < 4; ++ni)
#pragma unroll
                    for (int r = 0; r < 4; ++r) {
                        int row = row0 + wm * 64 + mi * 16 + quad * 4 + r;
                        int col = col0 + wn * 64 + ni * 16 + l16;
                        ((float*)Cmain)[(long)row * ldc + col] = acc[mi][ni][r];
                    }
        } else {
            // LDS-staged coalesced epilogue
            __syncthreads();                        // staging reads all done
            bf16* Ce = (bf16*)smem;                 // [128][132]
#pragma unroll
            for (int mi = 0; mi < 4; ++mi) {
                const int row = wm * 64 + mi * 16 + quad * 4;
#pragma unroll
                for (int ni = 0; ni < 4; ++ni) {
                    const int col = wn * 64 + ni * 16 + l16;
#pragma unroll
                    for (int r = 0; r < 4; ++r)
                        Ce[(row + r) * 132 + col] = (bf16)acc[mi][ni][r];
                }
            }
            __syncthreads();
            const int prow = tid >> 4;              // 0..15
            const int pc   = (tid & 15) * 8;        // bf16 col units
#pragma unroll
            for (int p = 0; p < 8; ++p) {
                const int row_l = p * 16 + prow;
                uint2 w0 = *reinterpret_cast<const uint2*>(&Ce[row_l * 132 + pc]);
                uint2 w1 = *reinterpret_cast<const uint2*>(&Ce[row_l * 132 + pc + 4]);
                uint4 w; w.x = w0.x; w.y = w0.y; w.z = w1.x; w.w = w1.y;
                *reinterpret_cast<uint4*>(
                    (bf16*)Cmain + (long)(row0 + row_l) * ldc + col0 + pc) = w;
            }
        }
    } else {
        // V store in Vt[bh][d][tc*64 + sigma(tloc)] layout (unswapped acc)
        const int h  = (col0 - split_col + wn * 64) >> 6;   // wave-uniform
        const int bq = row0 >> 11;
        const int tc = ((row0 & 2047) >> 6) + wm;
#pragma unroll
        for (int ni = 0; ni < 4; ++ni) {
            long vrow = (long)(bq * NH + h) * 64 + ni * 16 + l16;
#pragma unroll
            for (int mi = 0; mi < 4; ++mi) {
                bf16 outv[4];
#pragma unroll
                for (int r = 0; r < 4; ++r) outv[r] = (bf16)acc[mi][ni][r];
                *reinterpret_cast<uint2*>(&Cv[vrow * 2048 + tc * 64 + quad * 16 + mi * 4]) =
                    *reinterpret_cast<uint2*>(outv);
            }
        }
        // fused Vtile: per d-col sum over the 64-token tile
#pragma unroll
        for (int ni = 0; ni < 4; ++ni) {
            float s = 0.f;
#pragma unroll
            for (int mi = 0; mi < 4; ++mi)
#pragma unroll
                for (int r = 0; r < 4; ++r) s += acc[mi][ni][r];
            s += __shfl_xor(s, 16, 64);
            s += __shfl_xor(s, 32, 64);
            if (quad == 0)
                Vtile[((long)(bq * NH + h) * 32 + tc) * 64 + ni * 16 + l16] = s;
        }
    }
}

// =====================================================================
// GEMM 128x64 (gemm2): grid 512 = 2 blocks/CU. acc[4][2]. (v9 verbatim)
// =====================================================================
__global__ __launch_bounds__(256)
void gemm_bt64(const bf16* __restrict__ A0, const bf16* __restrict__ A1,
               const bf16* __restrict__ B0, const bf16* __restrict__ B1,
               void* __restrict__ C, const int* __restrict__ flag,
               int M, int N, int K, int lda, int ldb, int ldc, int cf32_dyn) {
    __shared__ bf16 As[2][128 * 32];
    __shared__ bf16 Bs[2][64 * 32];

    const int f = *flag;
    const bf16* A = f ? A1 : A0;
    const bf16* B = f ? B1 : B0;
    const int cf32 = cf32_dyn & f;

    const int tid  = threadIdx.x;
    const int lane = tid & 63;
    const int wave = tid >> 6;
    const int wm   = wave >> 1;
    const int wn   = wave & 1;
    const int quad = lane >> 4;
    const int l16  = lane & 15;

    const int row0 = blockIdx.y * 128;
    const int col0 = blockIdx.x * 64;

    const int srow = tid >> 2;
    const int skk  = (tid & 3) * 8;

    const bf16* Ap = A + (long)(row0 + srow) * lda + skk;
    const bf16* Bp = B + (long)(col0 + srow) * ldb + skk;

    auto stage = [&](int k0, int buf) {
        glds16(Ap + k0,                  &As[buf][wave * 512]);
        glds16(Ap + (long)64 * lda + k0, &As[buf][wave * 512 + 2048]);
        glds16(Bp + k0,                  &Bs[buf][wave * 512]);
    };

    f32x4 acc[4][2] = {};
    stage(0, 0);

    for (int k0 = 0; k0 < K; k0 += 32) {
        const int buf = (k0 >> 5) & 1;
        __syncthreads();
        if (k0 + 32 < K) stage(k0 + 32, buf ^ 1);

        const bf16* Ac = As[buf];
        const bf16* Bc = Bs[buf];
        bf16x8 af[4], bfv[2];
#pragma unroll
        for (int mi = 0; mi < 4; ++mi)
            af[mi] = *reinterpret_cast<const bf16x8*>(&Ac[(wm * 64 + mi * 16 + l16) * 32 + quad * 8]);
#pragma unroll
        for (int ni = 0; ni < 2; ++ni)
            bfv[ni] = *reinterpret_cast<const bf16x8*>(&Bc[(wn * 32 + ni * 16 + l16) * 32 + quad * 8]);
#pragma unroll
        for (int mi = 0; mi < 4; ++mi)
#pragma unroll
            for (int ni = 0; ni < 2; ++ni)
                acc[mi][ni] = __builtin_amdgcn_mfma_f32_16x16x32_bf16(af[mi], bfv[ni], acc[mi][ni], 0, 0, 0);
    }

#pragma unroll
    for (int mi = 0; mi < 4; ++mi)
#pragma unroll
        for (int ni = 0; ni < 2; ++ni)
#pragma unroll
            for (int r = 0; r < 4; ++r) {
                int row = row0 + wm * 64 + mi * 16 + quad * 4 + r;
                int col = col0 + wn * 32 + ni * 16 + l16;
                float v = acc[mi][ni][r];
                if (cf32) ((float*)C)[(long)row * ldc + col] = v;
                else      ((bf16*)C)[(long)row * ldc + col] = (bf16)v;
            }
}

// =====================================================================
// Flash attention v9 (unchanged, at its latency floor ~47us):
// 64q x 64k, 4 waves, 1024 blocks, 3 LDS buffers, depth-2 counted-vmcnt
// prefetch, cross-tile pipeline, Q pre-scaled, lp via ones-MFMA,
// in-block Vts suffix.
// =====================================================================
__global__ __launch_bounds__(256, 3)
void attn(bf16* __restrict__ qk, const bf16* __restrict__ Vt,
          const float* __restrict__ Vtile) {
    __shared__ bf16 Ks[3][64 * 64];
    __shared__ bf16 Vs[3][64 * 64];
    __shared__ float Vpart[4][64];

    const int tid  = threadIdx.x;
    const int lane = tid & 63;
    const int wave = tid >> 6;
    const int quad = lane >> 4;
    const int l16  = lane & 15;

    const int f2   = blockIdx.x;            // 0..1023
    const int xcd  = f2 & 7;
    const int slot = f2 >> 3;               // 0..127
    const int u    = slot & 3;              // {b, h&1}
    const int chunk = 31 - (slot >> 2);     // heavy first
    const int h = xcd * 2 + (u & 1);        // producer XCD = h>>1
    const int b = u >> 1;
    const int bh = b * 16 + h;
    const int q0 = chunk * 64;
    const long rbase = (long)b * TT;
    const int ktend = chunk + 1;

    const bf16* qp = qk + (rbase + q0 + wave * 16 + l16) * 2048 + h * HS;
    bf16x8 qf0 = *reinterpret_cast<const bf16x8*>(qp + quad * 8);
    bf16x8 qf1 = *reinterpret_cast<const bf16x8*>(qp + 32 + quad * 8);
#pragma unroll
    for (int j = 0; j < 8; ++j) {
        qf0[j] = (bf16)((float)qf0[j] * SCL2);
        qf1[j] = (bf16)((float)qf1[j] * SCL2);
    }

    f32x4 O[4] = {};
    f32x4 lpacc = {};
    const short one_bf16 = (short)0x3F80;
    const s16x4 ones = {one_bf16, one_bf16, one_bf16, one_bf16};

    const int rl  = lane >> 3;
    const int cs  = (lane & 7) ^ rl;
    const int row0dma = wave * 16 + rl;
    const bf16* kgb = qk + (rbase + row0dma) * 2048 + CC + h * HS + cs * 8;
    const bf16* vgb = Vt + ((long)(b * NH + h) * 64 + row0dma) * 2048 + cs * 8;
    const int sx = l16 & 7;

    auto stage = [&](int kt, int bi) {
        glds16(kgb + (long)(kt * 64) * 2048,     &Ks[bi][wave * 1024]);
        glds16(kgb + (long)(kt * 64 + 8) * 2048, &Ks[bi][wave * 1024 + 512]);
        glds16(vgb + kt * 64,                    &Vs[bi][wave * 1024]);
        glds16(vgb + 8 * 2048 + kt * 64,         &Vs[bi][wave * 1024 + 512]);
    };

    auto qkTile = [&](int bi, f32x4* Sn) {
        const bf16* Kc = Ks[bi];
        bf16x8 kf0[4], kf1[4];
#pragma unroll
        for (int g = 0; g < 4; ++g) {
            const int krow = g * 16 + l16;
            kf0[g] = *reinterpret_cast<const bf16x8*>(&Kc[krow * 64 + ((quad ^ sx) * 8)]);
            kf1[g] = *reinterpret_cast<const bf16x8*>(&Kc[krow * 64 + (((4 + quad) ^ sx) * 8)]);
        }
        __builtin_amdgcn_s_setprio(1);
#pragma unroll
        for (int g = 0; g < 4; ++g) {
            Sn[g] = __builtin_amdgcn_mfma_f32_16x16x32_bf16(kf0[g], qf0, Sn[g], 0, 0, 0);
            Sn[g] = __builtin_amdgcn_mfma_f32_16x16x32_bf16(kf1[g], qf1, Sn[g], 0, 0, 0);
        }
        __builtin_amdgcn_s_setprio(0);
    };
    auto vTile = [&](int bi, s16x4 vf[4][4]) {
        const bf16* Vc = Vs[bi];
#pragma unroll
        for (int dg = 0; dg < 4; ++dg) {
            const int vrow = dg * 16 + l16;
            union { uint4 u4; s16x4 s[2]; } ua, ub;
            ua.u4 = *reinterpret_cast<const uint4*>(&Vc[vrow * 64 + (((2 * quad) ^ sx) * 8)]);
            ub.u4 = *reinterpret_cast<const uint4*>(&Vc[vrow * 64 + (((2 * quad + 1) ^ sx) * 8)]);
            vf[dg][0] = ua.s[0]; vf[dg][1] = ua.s[1];
            vf[dg][2] = ub.s[0]; vf[dg][3] = ub.s[1];
        }
    };

    stage(0, 0);
    stage(ktend > 1 ? 1 : 0, 1);
    asm volatile("s_waitcnt vmcnt(4)" ::: "memory");
    __builtin_amdgcn_s_barrier();
    __builtin_amdgcn_sched_barrier(0);

    f32x4 Sc[4] = {};
    s16x4 vc[4][4] = {};
    qkTile(0, Sc);
    vTile(0, vc);

    int rb = 1;                 // buffer of tile kt+1
    int sb = 2;                 // slot for stage(kt+2)
    for (int kt = 0; kt < ktend; ++kt) {
        int nkt = kt + 2; nkt = (nkt < ktend) ? nkt : (ktend - 1);
        stage(nkt, sb);
        asm volatile("s_waitcnt vmcnt(4)" ::: "memory");
        __builtin_amdgcn_s_barrier();
        __builtin_amdgcn_sched_barrier(0);

        f32x4 Sn[4] = {};
        s16x4 vn[4][4] = {};
        if (kt + 1 < ktend) {
            qkTile(rb, Sn);
            vTile(rb, vn);
        }

        const bool dtile = (kt == ktend - 1);
        const int ql = wave * 16 + l16;
        s16x4 pk[4];
#pragma unroll
        for (int g = 0; g < 4; ++g) {
#pragma unroll
            for (int r = 0; r < 4; ++r) {
                float p = __builtin_exp2f(Sc[g][r]);
                if (dtile) {
                    int kl = g * 16 + quad * 4 + r;
                    p = (kl > ql) ? E10 : p;
                }
                union { bf16 b_; short s_; } u2;
                u2.b_ = (bf16)p;
                pk[g][r] = u2.s_;
            }
        }

        __builtin_amdgcn_s_setprio(1);
#pragma unroll
        for (int dg = 0; dg < 4; ++dg) {
            O[dg] = __builtin_amdgcn_mfma_f32_16x16x16bf16_1k(vc[dg][0], pk[0], O[dg], 0, 0, 0);
            O[dg] = __builtin_amdgcn_mfma_f32_16x16x16bf16_1k(vc[dg][1], pk[1], O[dg], 0, 0, 0);
            O[dg] = __builtin_amdgcn_mfma_f32_16x16x16bf16_1k(vc[dg][2], pk[2], O[dg], 0, 0, 0);
            O[dg] = __builtin_amdgcn_mfma_f32_16x16x16bf16_1k(vc[dg][3], pk[3], O[dg], 0, 0, 0);
        }
        lpacc = __builtin_amdgcn_mfma_f32_16x16x16bf16_1k(ones, pk[0], lpacc, 0, 0, 0);
        lpacc = __builtin_amdgcn_mfma_f32_16x16x16bf16_1k(ones, pk[1], lpacc, 0, 0, 0);
        lpacc = __builtin_amdgcn_mfma_f32_16x16x16bf16_1k(ones, pk[2], lpacc, 0, 0, 0);
        lpacc = __builtin_amdgcn_mfma_f32_16x16x16bf16_1k(ones, pk[3], lpacc, 0, 0, 0);
        __builtin_amdgcn_s_setprio(0);

#pragma unroll
        for (int g = 0; g < 4; ++g) Sc[g] = Sn[g];
#pragma unroll
        for (int dg = 0; dg < 4; ++dg)
#pragma unroll
            for (int j = 0; j < 4; ++j) vc[dg][j] = vn[dg][j];

        rb = (rb == 2) ? 0 : rb + 1;
        sb = (sb == 2) ? 0 : sb + 1;
    }

    // in-block Vts suffix: sum Vtile[bh][kt][d] for kt in [ktend,32)
    {
        float s = 0.f;
        for (int kt = ktend + wave; kt < 32; kt += 4)
            s += Vtile[((long)bh * 32 + kt) * 64 + lane];
        Vpart[wave][lane] = s;
    }
    __syncthreads();

    const int nfut = TT - ktend * 64;
    const float l = lpacc[0] + (float)nfut * E10;
    const float invl = 1.0f / l;

    bf16* yp = qk + (rbase + q0 + wave * 16 + l16) * 2048 + h * HS;
#pragma unroll
    for (int dg = 0; dg < 4; ++dg) {
        bf16 outv[4];
#pragma unroll
        for (int r = 0; r < 4; ++r) {
            const int d = dg * 16 + quad * 4 + r;
            float vts = Vpart[0][d] + Vpart[1][d] + Vpart[2][d] + Vpart[3][d];
            float o = O[dg][r] + E10 * vts;
            outv[r] = (bf16)(o * invl);
        }
        *reinterpret_cast<uint2*>(yp + dg * 16 + quad * 4) =
            *reinterpret_cast<uint2*>(outv);
    }
}

// =====================================================================
extern "C" void kernel_launch(void* const* d_in, const int* in_sizes, int n_in,
                              void* d_out, int out_size, void* d_ws, size_t ws_size,
                              hipStream_t stream) {
    const void* x      = d_in[0];
    const void* w_attn = d_in[1];
    const void* w_proj = d_in[2];

    // ws (~27.8 MB): qk | Vt | flag | (pad) | wp_cvt | Vtile
    char* ws = (char*)d_ws;
    bf16*  qk     = (bf16*)ws;                                    // 16,777,216 B
    bf16*  Vt     = (bf16*)(ws + (size_t)MT * 2048 * 2);          //  8,388,608 B
    char*  p2     = ws + (size_t)MT * 2048 * 2 + (size_t)32 * 64 * 2048 * 2;
    int*   flag   = (int*)p2;
    bf16*  wp_cvt = (bf16*)(p2 + 256 + 32 * 33 * 64 * 4);         //  2,097,152 B
    float* Vtile  = (float*)((char*)wp_cvt + (size_t)CC * CC * 2);//    262,144 B

    // d_out scratch (dead-by-ordering): x_cvt/wa_cvt consumed by gemm1;
    // gemm2 is the only writer of d_out afterwards.
    bf16* x_cvt  = (bf16*)d_out;
    bf16* wa_cvt = (bf16*)d_out + (size_t)MT * CC;

    // convert (with inline dtype detect; block 0 publishes flag)
    convert_all<<<(NX8 + NWA8 + NWP8) / 256, 256, 0, stream>>>(
        (const float*)x, (const float*)w_attn, (const float*)w_proj,
        x_cvt, wa_cvt, wp_cvt, flag);

    // gemm1: qkv projection. cols<2048 (Q,K) -> qk via LDS-staged wide
    // stores; cols>=2048 (V) -> Vt (sigma-packed) + fused Vtile sums.
    gemm_bt<<<dim3(C3 / 128, MT / 128), 256, 0, stream>>>(
        (const bf16*)x, x_cvt, (const bf16*)w_attn, wa_cvt, qk, Vt, Vtile, flag,
        MT, C3, CC, CC, CC, /*ldc*/2048, /*split*/2048, /*cf32*/0);

    // attention (cross-tile pipelined, in-block Vts suffix); y -> Q cols
    attn<<<dim3(1024), 256, 0, stream>>>(qk, Vt, Vtile);

    // gemm2: out = y @ w_proj^T  [4096, 1024] — 128x64 tiles
    gemm_bt64<<<dim3(CC / 64, MT / 128), 256, 0, stream>>>(
        qk, qk, (const bf16*)w_proj, wp_cvt, d_out, flag,
        MT, CC, CC, /*lda*/2048, CC, CC, /*cf32*/1);
}

// Round 11
// 170.814 us; speedup vs baseline: 1.2228x; 1.0277x over previous
//
#include <hip/hip_runtime.h>
#include <hip/hip_bf16.h>
#include <stdint.h>

// ---- problem constants (B=2, T=2048, C=1024, H=16, hs=64) ----
#define BSZ   2
#define TT    2048
#define NH    16
#define HS    64
#define CC    1024
#define C3    3072
#define MT    4096            // B*T rows
#define E10   4.5399929762484854e-05f   // exp(-10)
#define SCL2  0.1803368801111204f       // 0.125 * log2(e)

typedef __bf16 bf16;
typedef __bf16 bf16x8 __attribute__((ext_vector_type(8)));
typedef float  f32x4  __attribute__((ext_vector_type(4)));
typedef short  s16x4  __attribute__((ext_vector_type(4)));

#define AS1 __attribute__((address_space(1)))
#define AS3 __attribute__((address_space(3)))

__device__ __forceinline__ void glds16(const bf16* g, bf16* l) {
    __builtin_amdgcn_global_load_lds((const AS1 void*)g, (AS3 void*)l, 16, 0, 0);
}

// =====================================================================
// convert_all with INLINE dtype detection: every block samples x[0:512)
// uint16 exponents, computes flag locally; block 0 publishes it.
// flag=0 -> bf16 inputs (no convert), flag=1 -> fp32 inputs.
// =====================================================================
#define NX8  (MT * CC / 8)          // 524288
#define NWA8 (C3 * CC / 8)          // 393216
#define NWP8 (CC * CC / 8)          // 131072
__global__ __launch_bounds__(256)
void convert_all(const float* __restrict__ x, const float* __restrict__ wa,
                 const float* __restrict__ wp, bf16* __restrict__ xd,
                 bf16* __restrict__ wad, bf16* __restrict__ wpd,
                 int* __restrict__ flag) {
    __shared__ int wsum[4];
    const int tid = threadIdx.x;
    const uint16_t* x16 = (const uint16_t*)x;
    int local = 0;
    {
        uint16_t u = x16[tid];
        int e = (u >> 7) & 0xFF; local += (e >= 96 && e <= 159);
        u = x16[tid + 256];
        e = (u >> 7) & 0xFF; local += (e >= 96 && e <= 159);
    }
    local += __shfl_xor(local, 1, 64);
    local += __shfl_xor(local, 2, 64);
    local += __shfl_xor(local, 4, 64);
    local += __shfl_xor(local, 8, 64);
    local += __shfl_xor(local, 16, 64);
    local += __shfl_xor(local, 32, 64);
    if ((tid & 63) == 0) wsum[tid >> 6] = local;
    __syncthreads();
    const int cnt = wsum[0] + wsum[1] + wsum[2] + wsum[3];
    const int f = (cnt >= 461) ? 0 : 1;
    if (blockIdx.x == 0 && tid == 0) *flag = f;
    if (f == 0) return;

    long i = (long)blockIdx.x * 256 + tid;
    const float* s; bf16* d; long off;
    if (i < NX8)             { s = x;  d = xd;  off = i; }
    else if (i < NX8 + NWA8) { s = wa; d = wad; off = i - NX8; }
    else                     { s = wp; d = wpd; off = i - NX8 - NWA8; }
    const float4* sp = reinterpret_cast<const float4*>(s) + off * 2;
    float4 a = sp[0], b = sp[1];
    bf16x8 r;
    r[0] = (bf16)a.x; r[1] = (bf16)a.y; r[2] = (bf16)a.z; r[3] = (bf16)a.w;
    r[4] = (bf16)b.x; r[5] = (bf16)b.y; r[6] = (bf16)b.z; r[7] = (bf16)b.w;
    reinterpret_cast<bf16x8*>(d)[off] = r;
}

// =====================================================================
// GEMM 128x128: C = A*B^T, dbuf single-barrier pipeline (v11 verbatim).
// Main-store path: LDS-staged epilogue (Ce[128][132] bf16, stride 132
// -> conflict-free scatter), then 8 coalesced 16B stores/thread.
// V-blocks keep sigma store + fused Vtile sums.
// =====================================================================
__global__ __launch_bounds__(256)
void gemm_bt(const bf16* __restrict__ A0, const bf16* __restrict__ A1,
             const bf16* __restrict__ B0, const bf16* __restrict__ B1,
             void* __restrict__ Cmain, bf16* __restrict__ Cv,
             float* __restrict__ Vtile,
             const int* __restrict__ flag,
             int M, int N, int K, int lda, int ldb, int ldc,
             int split_col, int cf32_dyn) {
    // union: staging (As 16KB | Bs 16KB) / epilogue Ce 128x132 bf16 (33792B)
    __shared__ __align__(16) char smem[33792];
    bf16* As0 = (bf16*)smem;            // [2][128*32]
    bf16* Bs0 = (bf16*)(smem + 16384);  // [2][128*32]

    const int f = *flag;
    const bf16* A = f ? A1 : A0;
    const bf16* B = f ? B1 : B0;
    const int cf32 = cf32_dyn & f;

    const int tid  = threadIdx.x;
    const int lane = tid & 63;
    const int wave = tid >> 6;
    const int wm   = wave >> 1;
    const int wn   = wave & 1;
    const int quad = lane >> 4;
    const int l16  = lane & 15;

    const int row0 = blockIdx.y * 128;
    const int col0 = blockIdx.x * 128;
    const bool mainblk = (split_col < 0 || col0 < split_col);

    const int srow = tid >> 2;
    const int skk  = (tid & 3) * 8;

    const bf16* Ap = A + (long)(row0 + srow) * lda + skk;
    const bf16* Bp = B + (long)(col0 + srow) * ldb + skk;

    auto stage = [&](int k0, int buf) {
        glds16(Ap + k0,                  As0 + buf * 4096 + wave * 512);
        glds16(Ap + (long)64 * lda + k0, As0 + buf * 4096 + wave * 512 + 2048);
        glds16(Bp + k0,                  Bs0 + buf * 4096 + wave * 512);
        glds16(Bp + (long)64 * ldb + k0, Bs0 + buf * 4096 + wave * 512 + 2048);
    };

    f32x4 acc[4][4] = {};
    stage(0, 0);

    for (int k0 = 0; k0 < K; k0 += 32) {
        const int buf = (k0 >> 5) & 1;
        __syncthreads();
        if (k0 + 32 < K) stage(k0 + 32, buf ^ 1);

        const bf16* Ac = As0 + buf * 4096;
        const bf16* Bc = Bs0 + buf * 4096;
        bf16x8 af[4], bfv[4];
#pragma unroll
        for (int mi = 0; mi < 4; ++mi)
            af[mi] = *reinterpret_cast<const bf16x8*>(&Ac[(wm * 64 + mi * 16 + l16) * 32 + quad * 8]);
#pragma unroll
        for (int ni = 0; ni < 4; ++ni)
            bfv[ni] = *reinterpret_cast<const bf16x8*>(&Bc[(wn * 64 + ni * 16 + l16) * 32 + quad * 8]);
#pragma unroll
        for (int mi = 0; mi < 4; ++mi)
#pragma unroll
            for (int ni = 0; ni < 4; ++ni)
                acc[mi][ni] = __builtin_amdgcn_mfma_f32_16x16x32_bf16(af[mi], bfv[ni], acc[mi][ni], 0, 0, 0);
    }

    if (mainblk) {
        if (cf32) {
            // fallback (unused by current launches): scalar f32 stores
#pragma unroll
            for (int mi = 0; mi < 4; ++mi)
#pragma unroll
                for (int ni = 0; ni < 4; ++ni)
#pragma unroll
                    for (int r = 0; r < 4; ++r) {
                        int row = row0 + wm * 64 + mi * 16 + quad * 4 + r;
                        int col = col0 + wn * 64 + ni * 16 + l16;
                        ((float*)Cmain)[(long)row * ldc + col] = acc[mi][ni][r];
                    }
        } else {
            // LDS-staged coalesced epilogue
            __syncthreads();                        // staging reads all done
            bf16* Ce = (bf16*)smem;                 // [128][132]
#pragma unroll
            for (int mi = 0; mi < 4; ++mi) {
                const int row = wm * 64 + mi * 16 + quad * 4;
#pragma unroll
                for (int ni = 0; ni < 4; ++ni) {
                    const int col = wn * 64 + ni * 16 + l16;
#pragma unroll
                    for (int r = 0; r < 4; ++r)
                        Ce[(row + r) * 132 + col] = (bf16)acc[mi][ni][r];
                }
            }
            __syncthreads();
            const int prow = tid >> 4;              // 0..15
            const int pc   = (tid & 15) * 8;        // bf16 col units
#pragma unroll
            for (int p = 0; p < 8; ++p) {
                const int row_l = p * 16 + prow;
                uint2 w0 = *reinterpret_cast<const uint2*>(&Ce[row_l * 132 + pc]);
                uint2 w1 = *reinterpret_cast<const uint2*>(&Ce[row_l * 132 + pc + 4]);
                uint4 w; w.x = w0.x; w.y = w0.y; w.z = w1.x; w.w = w1.y;
                *reinterpret_cast<uint4*>(
                    (bf16*)Cmain + (long)(row0 + row_l) * ldc + col0 + pc) = w;
            }
        }
    } else {
        // V store in Vt[bh][d][tc*64 + sigma(tloc)] layout (unswapped acc)
        const int h  = (col0 - split_col + wn * 64) >> 6;   // wave-uniform
        const int bq = row0 >> 11;
        const int tc = ((row0 & 2047) >> 6) + wm;
#pragma unroll
        for (int ni = 0; ni < 4; ++ni) {
            long vrow = (long)(bq * NH + h) * 64 + ni * 16 + l16;
#pragma unroll
            for (int mi = 0; mi < 4; ++mi) {
                bf16 outv[4];
#pragma unroll
                for (int r = 0; r < 4; ++r) outv[r] = (bf16)acc[mi][ni][r];
                *reinterpret_cast<uint2*>(&Cv[vrow * 2048 + tc * 64 + quad * 16 + mi * 4]) =
                    *reinterpret_cast<uint2*>(outv);
            }
        }
        // fused Vtile: per d-col sum over the 64-token tile
#pragma unroll
        for (int ni = 0; ni < 4; ++ni) {
            float s = 0.f;
#pragma unroll
            for (int mi = 0; mi < 4; ++mi)
#pragma unroll
                for (int r = 0; r < 4; ++r) s += acc[mi][ni][r];
            s += __shfl_xor(s, 16, 64);
            s += __shfl_xor(s, 32, 64);
            if (quad == 0)
                Vtile[((long)(bq * NH + h) * 32 + tc) * 64 + ni * 16 + l16] = s;
        }
    }
}

// =====================================================================
// GEMM 128x64 (gemm2): grid 512 = 2 blocks/CU. acc[4][2].
// v12: cf32 path gets the LDS-staged coalesced epilogue (Ce[128][68]
// f32, stride 68 -> 2-way-max aliasing = free), 8 x 16B stores/thread
// instead of 32 scalar 4B stores.
// =====================================================================
__global__ __launch_bounds__(256)
void gemm_bt64(const bf16* __restrict__ A0, const bf16* __restrict__ A1,
               const bf16* __restrict__ B0, const bf16* __restrict__ B1,
               void* __restrict__ C, const int* __restrict__ flag,
               int M, int N, int K, int lda, int ldb, int ldc, int cf32_dyn) {
    // union: staging (As 16KB | Bs 8KB) / epilogue Ce 128x68 f32 (34816B)
    __shared__ __align__(16) char smem[34816];
    bf16* As0 = (bf16*)smem;            // [2][128*32]
    bf16* Bs0 = (bf16*)(smem + 16384);  // [2][64*32]

    const int f = *flag;
    const bf16* A = f ? A1 : A0;
    const bf16* B = f ? B1 : B0;
    const int cf32 = cf32_dyn & f;

    const int tid  = threadIdx.x;
    const int lane = tid & 63;
    const int wave = tid >> 6;
    const int wm   = wave >> 1;
    const int wn   = wave & 1;
    const int quad = lane >> 4;
    const int l16  = lane & 15;

    const int row0 = blockIdx.y * 128;
    const int col0 = blockIdx.x * 64;

    const int srow = tid >> 2;
    const int skk  = (tid & 3) * 8;

    const bf16* Ap = A + (long)(row0 + srow) * lda + skk;
    const bf16* Bp = B + (long)(col0 + srow) * ldb + skk;

    auto stage = [&](int k0, int buf) {
        glds16(Ap + k0,                  As0 + buf * 4096 + wave * 512);
        glds16(Ap + (long)64 * lda + k0, As0 + buf * 4096 + wave * 512 + 2048);
        glds16(Bp + k0,                  Bs0 + buf * 2048 + wave * 512);
    };

    f32x4 acc[4][2] = {};
    stage(0, 0);

    for (int k0 = 0; k0 < K; k0 += 32) {
        const int buf = (k0 >> 5) & 1;
        __syncthreads();
        if (k0 + 32 < K) stage(k0 + 32, buf ^ 1);

        const bf16* Ac = As0 + buf * 4096;
        const bf16* Bc = Bs0 + buf * 2048;
        bf16x8 af[4], bfv[2];
#pragma unroll
        for (int mi = 0; mi < 4; ++mi)
            af[mi] = *reinterpret_cast<const bf16x8*>(&Ac[(wm * 64 + mi * 16 + l16) * 32 + quad * 8]);
#pragma unroll
        for (int ni = 0; ni < 2; ++ni)
            bfv[ni] = *reinterpret_cast<const bf16x8*>(&Bc[(wn * 32 + ni * 16 + l16) * 32 + quad * 8]);
#pragma unroll
        for (int mi = 0; mi < 4; ++mi)
#pragma unroll
            for (int ni = 0; ni < 2; ++ni)
                acc[mi][ni] = __builtin_amdgcn_mfma_f32_16x16x32_bf16(af[mi], bfv[ni], acc[mi][ni], 0, 0, 0);
    }

    if (cf32) {
        // LDS-staged coalesced f32 epilogue
        __syncthreads();
        float* Ce = (float*)smem;               // [128][68]
#pragma unroll
        for (int mi = 0; mi < 4; ++mi) {
            const int row = wm * 64 + mi * 16 + quad * 4;
#pragma unroll
            for (int ni = 0; ni < 2; ++ni) {
                const int col = wn * 32 + ni * 16 + l16;
#pragma unroll
                for (int r = 0; r < 4; ++r)
                    Ce[(row + r) * 68 + col] = acc[mi][ni][r];
            }
        }
        __syncthreads();
        const int prow = tid >> 4;              // 0..15
        const int pcf  = (tid & 15) * 4;        // f32 col units
#pragma unroll
        for (int p = 0; p < 8; ++p) {
            const int row_l = p * 16 + prow;
            f32x4 w = *reinterpret_cast<const f32x4*>(&Ce[row_l * 68 + pcf]);
            *reinterpret_cast<f32x4*>(
                (float*)C + (long)(row0 + row_l) * ldc + col0 + pcf) = w;
        }
    } else {
#pragma unroll
        for (int mi = 0; mi < 4; ++mi)
#pragma unroll
            for (int ni = 0; ni < 2; ++ni)
#pragma unroll
                for (int r = 0; r < 4; ++r) {
                    int row = row0 + wm * 64 + mi * 16 + quad * 4 + r;
                    int col = col0 + wn * 32 + ni * 16 + l16;
                    ((bf16*)C)[(long)row * ldc + col] = (bf16)acc[mi][ni][r];
                }
    }
}

// =====================================================================
// Flash attention v12: v9 structure (64q x 64k, 4 waves, 1024 blocks,
// 3 LDS buffers, depth-2 counted-vmcnt prefetch, cross-tile pipeline,
// Q pre-scaled, lp via ones-MFMA, in-block Vts suffix)
// + VALU diet 2: loop unrolled by 2 with role-swapped register sets
//   (kills 32 v_mov/tile of rotation), qkTile overwrites via
//   mfma(.., ZERO) (kills 16 zero-movs/tile).
// =====================================================================
__global__ __launch_bounds__(256, 3)
void attn(bf16* __restrict__ qk, const bf16* __restrict__ Vt,
          const float* __restrict__ Vtile) {
    __shared__ bf16 Ks[3][64 * 64];
    __shared__ bf16 Vs[3][64 * 64];
    __shared__ float Vpart[4][64];

    const int tid  = threadIdx.x;
    const int lane = tid & 63;
    const int wave = tid >> 6;
    const int quad = lane >> 4;
    const int l16  = lane & 15;

    const int f2   = blockIdx.x;            // 0..1023
    const int xcd  = f2 & 7;
    const int slot = f2 >> 3;               // 0..127
    const int u    = slot & 3;              // {b, h&1}
    const int chunk = 31 - (slot >> 2);     // heavy first
    const int h = xcd * 2 + (u & 1);        // producer XCD = h>>1
    const int b = u >> 1;
    const int bh = b * 16 + h;
    const int q0 = chunk * 64;
    const long rbase = (long)b * TT;
    const int ktend = chunk + 1;

    const bf16* qp = qk + (rbase + q0 + wave * 16 + l16) * 2048 + h * HS;
    bf16x8 qf0 = *reinterpret_cast<const bf16x8*>(qp + quad * 8);
    bf16x8 qf1 = *reinterpret_cast<const bf16x8*>(qp + 32 + quad * 8);
#pragma unroll
    for (int j = 0; j < 8; ++j) {
        qf0[j] = (bf16)((float)qf0[j] * SCL2);
        qf1[j] = (bf16)((float)qf1[j] * SCL2);
    }

    f32x4 O[4] = {};
    f32x4 lpacc = {};
    const short one_bf16 = (short)0x3F80;
    const s16x4 ones = {one_bf16, one_bf16, one_bf16, one_bf16};
    const f32x4 FZ = {0.f, 0.f, 0.f, 0.f};

    const int rl  = lane >> 3;
    const int cs  = (lane & 7) ^ rl;
    const int row0dma = wave * 16 + rl;
    const bf16* kgb = qk + (rbase + row0dma) * 2048 + CC + h * HS + cs * 8;
    const bf16* vgb = Vt + ((long)(b * NH + h) * 64 + row0dma) * 2048 + cs * 8;
    const int sx = l16 & 7;

    auto stage = [&](int kt, int bi) {
        glds16(kgb + (long)(kt * 64) * 2048,     &Ks[bi][wave * 1024]);
        glds16(kgb + (long)(kt * 64 + 8) * 2048, &Ks[bi][wave * 1024 + 512]);
        glds16(vgb + kt * 64,                    &Vs[bi][wave * 1024]);
        glds16(vgb + 8 * 2048 + kt * 64,         &Vs[bi][wave * 1024 + 512]);
    };

    auto qkTile = [&](int bi, f32x4 (&Sn)[4]) {
        const bf16* Kc = Ks[bi];
        bf16x8 kf0[4], kf1[4];
#pragma unroll
        for (int g = 0; g < 4; ++g) {
            const int krow = g * 16 + l16;
            kf0[g] = *reinterpret_cast<const bf16x8*>(&Kc[krow * 64 + ((quad ^ sx) * 8)]);
            kf1[g] = *reinterpret_cast<const bf16x8*>(&Kc[krow * 64 + (((4 + quad) ^ sx) * 8)]);
        }
        __builtin_amdgcn_s_setprio(1);
#pragma unroll
        for (int g = 0; g < 4; ++g) {
            Sn[g] = __builtin_amdgcn_mfma_f32_16x16x32_bf16(kf0[g], qf0, FZ, 0, 0, 0);
            Sn[g] = __builtin_amdgcn_mfma_f32_16x16x32_bf16(kf1[g], qf1, Sn[g], 0, 0, 0);
        }
        __builtin_amdgcn_s_setprio(0);
    };
    auto vTile = [&](int bi, s16x4 (&vf)[4][4]) {
        const bf16* Vc = Vs[bi];
#pragma unroll
        for (int dg = 0; dg < 4; ++dg) {
            const int vrow = dg * 16 + l16;
            union { uint4 u4; s16x4 s[2]; } ua, ub;
            ua.u4 = *reinterpret_cast<const uint4*>(&Vc[vrow * 64 + (((2 * quad) ^ sx) * 8)]);
            ub.u4 = *reinterpret_cast<const uint4*>(&Vc[vrow * 64 + (((2 * quad + 1) ^ sx) * 8)]);
            vf[dg][0] = ua.s[0]; vf[dg][1] = ua.s[1];
            vf[dg][2] = ub.s[0]; vf[dg][3] = ub.s[1];
        }
    };

    f32x4 SA[4], SB[4];
    s16x4 vA[4][4], vB[4][4];

    // per-iteration body: process tile kt from (Scur,vcur); prefetch
    // tile kt+1 into (Snxt,vnxt); stage tile kt+2.
    auto body = [&](int kt, f32x4 (&Scur)[4], s16x4 (&vcur)[4][4],
                    f32x4 (&Snxt)[4], s16x4 (&vnxt)[4][4]) {
        int nkt = kt + 2; nkt = (nkt < ktend) ? nkt : (ktend - 1);
        stage(nkt, (kt + 2) % 3);
        asm volatile("s_waitcnt vmcnt(4)" ::: "memory");
        __builtin_amdgcn_s_barrier();
        __builtin_amdgcn_sched_barrier(0);

        if (kt + 1 < ktend) {
            qkTile((kt + 1) % 3, Snxt);
            vTile((kt + 1) % 3, vnxt);
        }

        const bool dtile = (kt == ktend - 1);
        const int ql = wave * 16 + l16;
        s16x4 pk[4];
#pragma unroll
        for (int g = 0; g < 4; ++g) {
#pragma unroll
            for (int r = 0; r < 4; ++r) {
                float p = __builtin_exp2f(Scur[g][r]);
                if (dtile) {
                    int kl = g * 16 + quad * 4 + r;
                    p = (kl > ql) ? E10 : p;
                }
                union { bf16 b_; short s_; } u2;
                u2.b_ = (bf16)p;
                pk[g][r] = u2.s_;
            }
        }

        __builtin_amdgcn_s_setprio(1);
#pragma unroll
        for (int dg = 0; dg < 4; ++dg) {
            O[dg] = __builtin_amdgcn_mfma_f32_16x16x16bf16_1k(vcur[dg][0], pk[0], O[dg], 0, 0, 0);
            O[dg] = __builtin_amdgcn_mfma_f32_16x16x16bf16_1k(vcur[dg][1], pk[1], O[dg], 0, 0, 0);
            O[dg] = __builtin_amdgcn_mfma_f32_16x16x16bf16_1k(vcur[dg][2], pk[2], O[dg], 0, 0, 0);
            O[dg] = __builtin_amdgcn_mfma_f32_16x16x16bf16_1k(vcur[dg][3], pk[3], O[dg], 0, 0, 0);
        }
        lpacc = __builtin_amdgcn_mfma_f32_16x16x16bf16_1k(ones, pk[0], lpacc, 0, 0, 0);
        lpacc = __builtin_amdgcn_mfma_f32_16x16x16bf16_1k(ones, pk[1], lpacc, 0, 0, 0);
        lpacc = __builtin_amdgcn_mfma_f32_16x16x16bf16_1k(ones, pk[2], lpacc, 0, 0, 0);
        lpacc = __builtin_amdgcn_mfma_f32_16x16x16bf16_1k(ones, pk[3], lpacc, 0, 0, 0);
        __builtin_amdgcn_s_setprio(0);
    };

    // prologue
    stage(0, 0);
    stage(ktend > 1 ? 1 : 0, 1);
    asm volatile("s_waitcnt vmcnt(4)" ::: "memory");
    __builtin_amdgcn_s_barrier();
    __builtin_amdgcn_sched_barrier(0);
    qkTile(0, SA);
    vTile(0, vA);

    // unrolled-by-2 main loop (role-swapped register sets, no rotation)
    int kt = 0;
    while (true) {
        body(kt, SA, vA, SB, vB);
        if (++kt >= ktend) break;
        body(kt, SB, vB, SA, vA);
        if (++kt >= ktend) break;
    }

    // in-block Vts suffix: sum Vtile[bh][kt][d] for kt in [ktend,32)
    {
        float s = 0.f;
        for (int k2 = ktend + wave; k2 < 32; k2 += 4)
            s += Vtile[((long)bh * 32 + k2) * 64 + lane];
        Vpart[wave][lane] = s;
    }
    __syncthreads();

    const int nfut = TT - ktend * 64;
    const float l = lpacc[0] + (float)nfut * E10;
    const float invl = 1.0f / l;

    bf16* yp = qk + (rbase + q0 + wave * 16 + l16) * 2048 + h * HS;
#pragma unroll
    for (int dg = 0; dg < 4; ++dg) {
        bf16 outv[4];
#pragma unroll
        for (int r = 0; r < 4; ++r) {
            const int d = dg * 16 + quad * 4 + r;
            float vts = Vpart[0][d] + Vpart[1][d] + Vpart[2][d] + Vpart[3][d];
            float o = O[dg][r] + E10 * vts;
            outv[r] = (bf16)(o * invl);
        }
        *reinterpret_cast<uint2*>(yp + dg * 16 + quad * 4) =
            *reinterpret_cast<uint2*>(outv);
    }
}

// =====================================================================
extern "C" void kernel_launch(void* const* d_in, const int* in_sizes, int n_in,
                              void* d_out, int out_size, void* d_ws, size_t ws_size,
                              hipStream_t stream) {
    const void* x      = d_in[0];
    const void* w_attn = d_in[1];
    const void* w_proj = d_in[2];

    // ws (~27.8 MB): qk | Vt | flag | (pad) | wp_cvt | Vtile
    char* ws = (char*)d_ws;
    bf16*  qk     = (bf16*)ws;                                    // 16,777,216 B
    bf16*  Vt     = (bf16*)(ws + (size_t)MT * 2048 * 2);          //  8,388,608 B
    char*  p2     = ws + (size_t)MT * 2048 * 2 + (size_t)32 * 64 * 2048 * 2;
    int*   flag   = (int*)p2;
    bf16*  wp_cvt = (bf16*)(p2 + 256 + 32 * 33 * 64 * 4);         //  2,097,152 B
    float* Vtile  = (float*)((char*)wp_cvt + (size_t)CC * CC * 2);//    262,144 B

    // d_out scratch (dead-by-ordering): x_cvt/wa_cvt consumed by gemm1;
    // gemm2 is the only writer of d_out afterwards.
    bf16* x_cvt  = (bf16*)d_out;
    bf16* wa_cvt = (bf16*)d_out + (size_t)MT * CC;

    // convert (with inline dtype detect; block 0 publishes flag)
    convert_all<<<(NX8 + NWA8 + NWP8) / 256, 256, 0, stream>>>(
        (const float*)x, (const float*)w_attn, (const float*)w_proj,
        x_cvt, wa_cvt, wp_cvt, flag);

    // gemm1: qkv projection. cols<2048 (Q,K) -> qk via LDS-staged wide
    // stores; cols>=2048 (V) -> Vt (sigma-packed) + fused Vtile sums.
    gemm_bt<<<dim3(C3 / 128, MT / 128), 256, 0, stream>>>(
        (const bf16*)x, x_cvt, (const bf16*)w_attn, wa_cvt, qk, Vt, Vtile, flag,
        MT, C3, CC, CC, CC, /*ldc*/2048, /*split*/2048, /*cf32*/0);

    // attention (cross-tile pipelined, in-block Vts suffix); y -> Q cols
    attn<<<dim3(1024), 256, 0, stream>>>(qk, Vt, Vtile);

    // gemm2: out = y @ w_proj^T  [4096, 1024] — 128x64 tiles,
    // LDS-staged coalesced f32 epilogue
    gemm_bt64<<<dim3(CC / 64, MT / 128), 256, 0, stream>>>(
        qk, qk, (const bf16*)w_proj, wp_cvt, d_out, flag,
        MT, CC, CC, /*lda*/2048, CC, CC, /*cf32*/1);
}